// Round 3
// baseline (422.973 us; speedup 1.0000x reference)
//
#include <hip/hip_runtime.h>

// VQ argmin, bit-replicating numpy fp32 reference (see R2).
// R3: 8x8 register tile, square wave tiling (8tn x 8tm per wave) for
// LDS broadcast; split-K codes 4-way for grid occupancy; merge+gather kernel.
// B=16 D=256 H=W=32 -> n=16384 pixels; K=2048 codes.

#define D_    256
#define K_    2048
#define HW_   1024
#define MT    64      // pixels per block (vq_k)
#define NT    256     // codes per LDS chunk
#define KT    32      // dims per k-chunk
#define SPLIT 4
#define KS    (K_ / SPLIT)   // 512 codes per block
#define CST   258     // cs row stride: even align, 2-way banks only (free)
#define NPIX  16384

// numpy pairwise combine of 8 accumulators
__device__ __forceinline__ float pw8(const float r[8]) {
    float t01 = __fadd_rn(r[0], r[1]);
    float t23 = __fadd_rn(r[2], r[3]);
    float L   = __fadd_rn(t01, t23);
    float t45 = __fadd_rn(r[4], r[5]);
    float t67 = __fadd_rn(r[6], r[7]);
    float R   = __fadd_rn(t45, t67);
    return __fadd_rn(L, R);
}

__global__ __launch_bounds__(256) void bn_k(const float* __restrict__ cb,
                                            float* __restrict__ Bn) {
    int row = blockIdx.x * 256 + threadIdx.x;
    const float4* p = reinterpret_cast<const float4*>(cb + (size_t)row * D_);
    float rA[8], rB[8];
    #pragma unroll
    for (int j = 0; j < 8; ++j) { rA[j] = 0.f; rB[j] = 0.f; }
    #pragma unroll
    for (int q = 0; q < 64; ++q) {
        float4 v = p[q];
        float pv[4] = {__fmul_rn(v.x, v.x), __fmul_rn(v.y, v.y),
                       __fmul_rn(v.z, v.z), __fmul_rn(v.w, v.w)};
        if (q < 32) {
            #pragma unroll
            for (int l = 0; l < 4; ++l) rA[(4 * q + l) & 7] = __fadd_rn(rA[(4 * q + l) & 7], pv[l]);
        } else {
            #pragma unroll
            for (int l = 0; l < 4; ++l) rB[(4 * q + l) & 7] = __fadd_rn(rB[(4 * q + l) & 7], pv[l]);
        }
    }
    Bn[row] = __fadd_rn(pw8(rA), pw8(rB));
}

__global__ __launch_bounds__(256) void an_k(const float* __restrict__ z,
                                            float* __restrict__ An) {
    __shared__ float ls[KT][256];
    int b      = blockIdx.x >> 2;
    int hwbase = (blockIdx.x & 3) << 8;
    const float* zb = z + (size_t)b * (D_ * HW_) + hwbase;
    int tid = threadIdx.x;
    float rA[8], rB[8];
    #pragma unroll
    for (int j = 0; j < 8; ++j) { rA[j] = 0.f; rB[j] = 0.f; }
    for (int kc = 0; kc < 8; ++kc) {
        __syncthreads();
        #pragma unroll
        for (int it = 0; it < 8; ++it) {
            int u  = (it << 8) + tid;
            int dd = u >> 6;
            int m4 = u & 63;
            float4 v = *reinterpret_cast<const float4*>(
                zb + (size_t)(kc * KT + dd) * HW_ + (m4 << 2));
            *reinterpret_cast<float4*>(&ls[dd][m4 << 2]) = v;
        }
        __syncthreads();
        if (kc < 4) {
            #pragma unroll
            for (int dd = 0; dd < 32; ++dd) {
                float v = ls[dd][tid];
                rA[dd & 7] = __fadd_rn(rA[dd & 7], __fmul_rn(v, v));
            }
        } else {
            #pragma unroll
            for (int dd = 0; dd < 32; ++dd) {
                float v = ls[dd][tid];
                rB[dd & 7] = __fadd_rn(rB[dd & 7], __fmul_rn(v, v));
            }
        }
    }
    An[(size_t)b * HW_ + hwbase + tid] = __fadd_rn(pw8(rA), pw8(rB));
}

// main GEMM+argmin over a K/SPLIT slice of codes
__global__ __launch_bounds__(256, 3) void vq_k(const float* __restrict__ z,
                                               const float* __restrict__ cb,
                                               const float* __restrict__ An,
                                               const float* __restrict__ Bn,
                                               float* __restrict__ pscore,
                                               int* __restrict__ pidx) {
    __shared__ float smem[KT * MT + KT * CST];   // zs | cs ; aliased for reduce
    float* zs = smem;                 // [KT][MT] stride 64
    float* cs = smem + KT * MT;       // [KT][CST]
    float* rs = smem;                 // [MT][33]  (aliased after barrier)
    int*   ri = (int*)(smem + MT * 33);
    int*   idxs = (int*)(smem + 2 * MT * 33);

    const int tid = threadIdx.x;
    const int wv  = tid >> 6;
    const int tn  = (tid & 7) | (wv << 3);       // [0,32) n-group (wave-uniform high bits)
    const int tm  = (tid >> 3) & 7;              // [0,8)  m-group
    const int blk = blockIdx.x;
    const int p   = blk >> 2;                    // pixel-block [0,256)
    const int s   = blk & 3;                     // K-split slice
    const int b      = p >> 4;
    const int hwbase = (p & 15) << 6;
    const float* zbase = z + (size_t)b * (D_ * HW_) + hwbase;
    const float* cbS   = cb + (size_t)s * KS * D_;

    float an[8];
    #pragma unroll
    for (int i = 0; i < 8; ++i)
        an[i] = An[(size_t)b * HW_ + hwbase + (tm << 3) + i];

    float bs[8]; int bi[8];
    #pragma unroll
    for (int i = 0; i < 8; ++i) { bs[i] = 1e30f; bi[i] = 0; }

    for (int nc = 0; nc < KS / NT; ++nc) {       // 2 chunks of 256 codes
        float acc[8][8];
        #pragma unroll
        for (int i = 0; i < 8; ++i)
            #pragma unroll
            for (int j = 0; j < 8; ++j) acc[i][j] = 0.f;

        for (int kc = 0; kc < D_ / KT; ++kc) {
            __syncthreads();
            {   // stage z: 32 dims x 64 pixels, 2 float4/thread, coalesced
                #pragma unroll
                for (int it = 0; it < 2; ++it) {
                    int u  = (it << 8) + tid;
                    int dd = u >> 4;
                    int m4 = u & 15;
                    float4 v = *reinterpret_cast<const float4*>(
                        zbase + (size_t)(kc * KT + dd) * HW_ + (m4 << 2));
                    *reinterpret_cast<float4*>(&zs[dd * MT + (m4 << 2)]) = v;
                }
            }
            {   // stage codes transposed: 256 codes x 32 dims
                const float* cbase = cbS + (size_t)(nc * NT) * D_ + kc * KT;
                #pragma unroll
                for (int it = 0; it < 8; ++it) {
                    int u  = (it << 8) + tid;
                    int nn = u >> 3;
                    int d4 = u & 7;
                    float4 v = *reinterpret_cast<const float4*>(
                        cbase + (size_t)nn * D_ + (d4 << 2));
                    int db = d4 << 2;
                    cs[(db + 0) * CST + nn] = v.x;
                    cs[(db + 1) * CST + nn] = v.y;
                    cs[(db + 2) * CST + nn] = v.z;
                    cs[(db + 3) * CST + nn] = v.w;
                }
            }
            __syncthreads();
            // ascending-k single-acc FMA chain — bit-matches sgemm
            #pragma unroll
            for (int d = 0; d < KT; ++d) {
                const float* zr = &zs[d * MT + (tm << 3)];
                float4 a0 = *reinterpret_cast<const float4*>(zr);
                float4 a1 = *reinterpret_cast<const float4*>(zr + 4);
                const float* crow = &cs[d * CST + (tn << 3)];
                float4 b0 = *reinterpret_cast<const float4*>(crow);
                float4 b1 = *reinterpret_cast<const float4*>(crow + 4);
                float av[8] = {a0.x, a0.y, a0.z, a0.w, a1.x, a1.y, a1.z, a1.w};
                float bv[8] = {b0.x, b0.y, b0.z, b0.w, b1.x, b1.y, b1.z, b1.w};
                #pragma unroll
                for (int i = 0; i < 8; ++i)
                    #pragma unroll
                    for (int j = 0; j < 8; ++j)
                        acc[i][j] = fmaf(av[i], bv[j], acc[i][j]);
            }
        }
        // fold: d = fp32( fp32(A+B) - 2*M ), ascending code index
        #pragma unroll
        for (int j = 0; j < 8; ++j) {
            int nl = (tn << 3) + j;
            int ng = s * KS + nc * NT + nl;
            float bn = Bn[ng];
            #pragma unroll
            for (int i = 0; i < 8; ++i) {
                float sc = __fsub_rn(__fadd_rn(an[i], bn),
                                     __fmul_rn(2.0f, acc[i][j]));
                if (sc < bs[i]) { bs[i] = sc; bi[i] = ng; }
            }
        }
    }

    __syncthreads();   // protect smem before aliasing
    #pragma unroll
    for (int i = 0; i < 8; ++i) {
        int m = (tm << 3) + i;
        rs[m * 33 + tn] = bs[i];
        ri[m * 33 + tn] = bi[i];
    }
    __syncthreads();
    if (tid < MT) {
        int   m    = tid;
        float best = rs[m * 33];
        int   bidx = ri[m * 33];
        for (int t = 1; t < 32; ++t) {
            float sv = rs[m * 33 + t];
            int   ix = ri[m * 33 + t];
            if (sv < best || (sv == best && ix < bidx)) { best = sv; bidx = ix; }
        }
        int g = b * HW_ + hwbase + m;
        pscore[s * NPIX + g] = best;
        pidx[s * NPIX + g]   = bidx;
    }
}

// merge SPLIT partials (first-min tiebreak) + gather output
__global__ __launch_bounds__(256) void fin_k(const float* __restrict__ cb,
                                             const float* __restrict__ pscore,
                                             const int* __restrict__ pidx,
                                             float* __restrict__ out) {
    __shared__ int idxs[MT];
    int tid = threadIdx.x;
    int p   = blockIdx.x;               // [0,256)
    int b      = p >> 4;
    int hwbase = (p & 15) << 6;
    if (tid < MT) {
        int g = b * HW_ + hwbase + tid;
        float best = pscore[g];
        int   bidx = pidx[g];
        #pragma unroll
        for (int s = 1; s < SPLIT; ++s) {
            float sv = pscore[s * NPIX + g];
            int   ix = pidx[s * NPIX + g];
            if (sv < best || (sv == best && ix < bidx)) { best = sv; bidx = ix; }
        }
        idxs[tid] = bidx;
    }
    __syncthreads();
    float* obase = out + (size_t)b * (D_ * HW_) + hwbase;
    #pragma unroll
    for (int it = 0; it < 16; ++it) {
        int u  = (it << 8) + tid;
        int dd = u >> 4;                // [0,256)
        int m4 = u & 15;
        int i0 = idxs[(m4 << 2) + 0];
        int i1 = idxs[(m4 << 2) + 1];
        int i2 = idxs[(m4 << 2) + 2];
        int i3 = idxs[(m4 << 2) + 3];
        float4 o;
        o.x = cb[(size_t)i0 * D_ + dd];
        o.y = cb[(size_t)i1 * D_ + dd];
        o.z = cb[(size_t)i2 * D_ + dd];
        o.w = cb[(size_t)i3 * D_ + dd];
        *reinterpret_cast<float4*>(obase + (size_t)dd * HW_ + (m4 << 2)) = o;
    }
}

extern "C" void kernel_launch(void* const* d_in, const int* in_sizes, int n_in,
                              void* d_out, int out_size, void* d_ws, size_t ws_size,
                              hipStream_t stream) {
    const float* z  = (const float*)d_in[0];   // 16*256*32*32
    const float* cb = (const float*)d_in[1];   // 2048*256
    float* An     = (float*)d_ws;                       // 16384
    float* Bn     = An + NPIX;                          // 2048
    float* pscore = Bn + K_;                            // 4*16384
    int*   pidx   = (int*)(pscore + SPLIT * NPIX);      // 4*16384
    float* out    = (float*)d_out;

    bn_k<<<dim3(K_ / 256), dim3(256), 0, stream>>>(cb, Bn);
    an_k<<<dim3(64), dim3(256), 0, stream>>>(z, An);
    vq_k<<<dim3(256 * SPLIT), dim3(256), 0, stream>>>(z, cb, An, Bn, pscore, pidx);
    fin_k<<<dim3(256), dim3(256), 0, stream>>>(cb, pscore, pidx, out);
}

// Round 4
// 402.878 us; speedup vs baseline: 1.0499x; 1.0499x over previous
//
#include <hip/hip_runtime.h>

// VQ argmin, bit-replicating numpy fp32 reference (see R2).
// R4: 8x8 register tile (R3) but with launch_bounds(256,2) to kill the
// VGPR spill R3's (256,3) caused (VGPR 84 -> acc spilled, 62MB scratch
// writes). bn+an fused into one launch. Split-K=4 + merge/gather kernel.
// B=16 D=256 H=W=32 -> n=16384 pixels; K=2048 codes.

#define D_    256
#define K_    2048
#define HW_   1024
#define MT    64      // pixels per block (vq_k)
#define NT    256     // codes per LDS chunk
#define KT    32      // dims per k-chunk
#define SPLIT 4
#define KS    (K_ / SPLIT)   // 512 codes per block
#define CST   258     // cs row stride: even align, 2-way banks only (free)
#define NPIX  16384

// numpy pairwise combine of 8 accumulators
__device__ __forceinline__ float pw8(const float r[8]) {
    float t01 = __fadd_rn(r[0], r[1]);
    float t23 = __fadd_rn(r[2], r[3]);
    float L   = __fadd_rn(t01, t23);
    float t45 = __fadd_rn(r[4], r[5]);
    float t67 = __fadd_rn(r[6], r[7]);
    float R   = __fadd_rn(t45, t67);
    return __fadd_rn(L, R);
}

// fused norms kernel: blocks [0,8) -> Bn (codebook rows), [8,72) -> An (pixels)
__global__ __launch_bounds__(256) void norms_k(const float* __restrict__ z,
                                               const float* __restrict__ cb,
                                               float* __restrict__ An,
                                               float* __restrict__ Bn) {
    __shared__ float ls[KT][256];
    int tid = threadIdx.x;
    if (blockIdx.x < 8) {
        int row = blockIdx.x * 256 + tid;
        const float4* p = reinterpret_cast<const float4*>(cb + (size_t)row * D_);
        float rA[8], rB[8];
        #pragma unroll
        for (int j = 0; j < 8; ++j) { rA[j] = 0.f; rB[j] = 0.f; }
        #pragma unroll
        for (int q = 0; q < 64; ++q) {
            float4 v = p[q];
            float pv[4] = {__fmul_rn(v.x, v.x), __fmul_rn(v.y, v.y),
                           __fmul_rn(v.z, v.z), __fmul_rn(v.w, v.w)};
            if (q < 32) {
                #pragma unroll
                for (int l = 0; l < 4; ++l)
                    rA[(4 * q + l) & 7] = __fadd_rn(rA[(4 * q + l) & 7], pv[l]);
            } else {
                #pragma unroll
                for (int l = 0; l < 4; ++l)
                    rB[(4 * q + l) & 7] = __fadd_rn(rB[(4 * q + l) & 7], pv[l]);
            }
        }
        Bn[row] = __fadd_rn(pw8(rA), pw8(rB));
    } else {
        int blk    = blockIdx.x - 8;               // [0,64)
        int b      = blk >> 2;
        int hwbase = (blk & 3) << 8;
        const float* zb = z + (size_t)b * (D_ * HW_) + hwbase;
        float rA[8], rB[8];
        #pragma unroll
        for (int j = 0; j < 8; ++j) { rA[j] = 0.f; rB[j] = 0.f; }
        for (int kc = 0; kc < 8; ++kc) {
            __syncthreads();
            #pragma unroll
            for (int it = 0; it < 8; ++it) {
                int u  = (it << 8) + tid;
                int dd = u >> 6;
                int m4 = u & 63;
                float4 v = *reinterpret_cast<const float4*>(
                    zb + (size_t)(kc * KT + dd) * HW_ + (m4 << 2));
                *reinterpret_cast<float4*>(&ls[dd][m4 << 2]) = v;
            }
            __syncthreads();
            if (kc < 4) {
                #pragma unroll
                for (int dd = 0; dd < 32; ++dd) {
                    float v = ls[dd][tid];
                    rA[dd & 7] = __fadd_rn(rA[dd & 7], __fmul_rn(v, v));
                }
            } else {
                #pragma unroll
                for (int dd = 0; dd < 32; ++dd) {
                    float v = ls[dd][tid];
                    rB[dd & 7] = __fadd_rn(rB[dd & 7], __fmul_rn(v, v));
                }
            }
        }
        An[(size_t)b * HW_ + hwbase + tid] = __fadd_rn(pw8(rA), pw8(rB));
    }
}

// main GEMM+argmin over a K/SPLIT slice of codes
__global__ __launch_bounds__(256, 2) void vq_k(const float* __restrict__ z,
                                               const float* __restrict__ cb,
                                               const float* __restrict__ An,
                                               const float* __restrict__ Bn,
                                               float* __restrict__ pscore,
                                               int* __restrict__ pidx) {
    __shared__ float smem[KT * MT + KT * CST];   // zs | cs ; aliased for reduce
    float* zs = smem;                 // [KT][MT] stride 64
    float* cs = smem + KT * MT;       // [KT][CST]
    float* rs = smem;                 // [MT][33]  (aliased after barrier)
    int*   ri = (int*)(smem + MT * 33);

    const int tid = threadIdx.x;
    const int wv  = tid >> 6;
    const int tn  = (tid & 7) | (wv << 3);       // [0,32) n-group
    const int tm  = (tid >> 3) & 7;              // [0,8)  m-group
    const int blk = blockIdx.x;
    const int p   = blk >> 2;                    // pixel-block [0,256)
    const int s   = blk & 3;                     // K-split slice
    const int b      = p >> 4;
    const int hwbase = (p & 15) << 6;
    const float* zbase = z + (size_t)b * (D_ * HW_) + hwbase;
    const float* cbS   = cb + (size_t)s * KS * D_;

    float an[8];
    #pragma unroll
    for (int i = 0; i < 8; ++i)
        an[i] = An[(size_t)b * HW_ + hwbase + (tm << 3) + i];

    float bs[8]; int bi[8];
    #pragma unroll
    for (int i = 0; i < 8; ++i) { bs[i] = 1e30f; bi[i] = 0; }

    for (int nc = 0; nc < KS / NT; ++nc) {       // 2 chunks of 256 codes
        float acc[8][8];
        #pragma unroll
        for (int i = 0; i < 8; ++i)
            #pragma unroll
            for (int j = 0; j < 8; ++j) acc[i][j] = 0.f;

        for (int kc = 0; kc < D_ / KT; ++kc) {
            __syncthreads();
            {   // stage z: 32 dims x 64 pixels, 2 float4/thread, coalesced
                #pragma unroll
                for (int it = 0; it < 2; ++it) {
                    int u  = (it << 8) + tid;
                    int dd = u >> 4;
                    int m4 = u & 15;
                    float4 v = *reinterpret_cast<const float4*>(
                        zbase + (size_t)(kc * KT + dd) * HW_ + (m4 << 2));
                    *reinterpret_cast<float4*>(&zs[dd * MT + (m4 << 2)]) = v;
                }
            }
            {   // stage codes transposed: 256 codes x 32 dims
                const float* cbase = cbS + (size_t)(nc * NT) * D_ + kc * KT;
                #pragma unroll
                for (int it = 0; it < 8; ++it) {
                    int u  = (it << 8) + tid;
                    int nn = u >> 3;
                    int d4 = u & 7;
                    float4 v = *reinterpret_cast<const float4*>(
                        cbase + (size_t)nn * D_ + (d4 << 2));
                    int db = d4 << 2;
                    cs[(db + 0) * CST + nn] = v.x;
                    cs[(db + 1) * CST + nn] = v.y;
                    cs[(db + 2) * CST + nn] = v.z;
                    cs[(db + 3) * CST + nn] = v.w;
                }
            }
            __syncthreads();
            // ascending-k single-acc FMA chain — bit-matches sgemm
            #pragma unroll
            for (int d = 0; d < KT; ++d) {
                const float* zr = &zs[d * MT + (tm << 3)];
                float4 a0 = *reinterpret_cast<const float4*>(zr);
                float4 a1 = *reinterpret_cast<const float4*>(zr + 4);
                const float* crow = &cs[d * CST + (tn << 3)];
                float4 b0 = *reinterpret_cast<const float4*>(crow);
                float4 b1 = *reinterpret_cast<const float4*>(crow + 4);
                float av[8] = {a0.x, a0.y, a0.z, a0.w, a1.x, a1.y, a1.z, a1.w};
                float bv[8] = {b0.x, b0.y, b0.z, b0.w, b1.x, b1.y, b1.z, b1.w};
                #pragma unroll
                for (int i = 0; i < 8; ++i)
                    #pragma unroll
                    for (int j = 0; j < 8; ++j)
                        acc[i][j] = fmaf(av[i], bv[j], acc[i][j]);
            }
        }
        // fold: d = fp32( fp32(A+B) - 2*M ), ascending code index
        #pragma unroll
        for (int j = 0; j < 8; ++j) {
            int nl = (tn << 3) + j;
            int ng = s * KS + nc * NT + nl;
            float bn = Bn[ng];
            #pragma unroll
            for (int i = 0; i < 8; ++i) {
                float sc = __fsub_rn(__fadd_rn(an[i], bn),
                                     __fmul_rn(2.0f, acc[i][j]));
                if (sc < bs[i]) { bs[i] = sc; bi[i] = ng; }
            }
        }
    }

    __syncthreads();   // protect smem before aliasing
    #pragma unroll
    for (int i = 0; i < 8; ++i) {
        int m = (tm << 3) + i;
        rs[m * 33 + tn] = bs[i];
        ri[m * 33 + tn] = bi[i];
    }
    __syncthreads();
    if (tid < MT) {
        int   m    = tid;
        float best = rs[m * 33];
        int   bidx = ri[m * 33];
        for (int t = 1; t < 32; ++t) {
            float sv = rs[m * 33 + t];
            int   ix = ri[m * 33 + t];
            if (sv < best || (sv == best && ix < bidx)) { best = sv; bidx = ix; }
        }
        int g = b * HW_ + hwbase + m;
        pscore[s * NPIX + g] = best;
        pidx[s * NPIX + g]   = bidx;
    }
}

// merge SPLIT partials (first-min tiebreak) + gather output
__global__ __launch_bounds__(256) void fin_k(const float* __restrict__ cb,
                                             const float* __restrict__ pscore,
                                             const int* __restrict__ pidx,
                                             float* __restrict__ out) {
    __shared__ int idxs[MT];
    int tid = threadIdx.x;
    int p   = blockIdx.x;               // [0,256)
    int b      = p >> 4;
    int hwbase = (p & 15) << 6;
    if (tid < MT) {
        int g = b * HW_ + hwbase + tid;
        float best = pscore[g];
        int   bidx = pidx[g];
        #pragma unroll
        for (int s = 1; s < SPLIT; ++s) {
            float sv = pscore[s * NPIX + g];
            int   ix = pidx[s * NPIX + g];
            if (sv < best || (sv == best && ix < bidx)) { best = sv; bidx = ix; }
        }
        idxs[tid] = bidx;
    }
    __syncthreads();
    float* obase = out + (size_t)b * (D_ * HW_) + hwbase;
    #pragma unroll
    for (int it = 0; it < 16; ++it) {
        int u  = (it << 8) + tid;
        int dd = u >> 4;                // [0,256)
        int m4 = u & 15;
        int i0 = idxs[(m4 << 2) + 0];
        int i1 = idxs[(m4 << 2) + 1];
        int i2 = idxs[(m4 << 2) + 2];
        int i3 = idxs[(m4 << 2) + 3];
        float4 o;
        o.x = cb[(size_t)i0 * D_ + dd];
        o.y = cb[(size_t)i1 * D_ + dd];
        o.z = cb[(size_t)i2 * D_ + dd];
        o.w = cb[(size_t)i3 * D_ + dd];
        *reinterpret_cast<float4*>(obase + (size_t)dd * HW_ + (m4 << 2)) = o;
    }
}

extern "C" void kernel_launch(void* const* d_in, const int* in_sizes, int n_in,
                              void* d_out, int out_size, void* d_ws, size_t ws_size,
                              hipStream_t stream) {
    const float* z  = (const float*)d_in[0];   // 16*256*32*32
    const float* cb = (const float*)d_in[1];   // 2048*256
    float* An     = (float*)d_ws;                       // 16384
    float* Bn     = An + NPIX;                          // 2048
    float* pscore = Bn + K_;                            // 4*16384
    int*   pidx   = (int*)(pscore + SPLIT * NPIX);      // 4*16384
    float* out    = (float*)d_out;

    norms_k<<<dim3(72), dim3(256), 0, stream>>>(z, cb, An, Bn);
    vq_k<<<dim3(256 * SPLIT), dim3(256), 0, stream>>>(z, cb, An, Bn, pscore, pidx);
    fin_k<<<dim3(256), dim3(256), 0, stream>>>(cb, pscore, pidx, out);
}